// Round 7
// baseline (382.090 us; speedup 1.0000x reference)
//
#include <hip/hip_runtime.h>
#include <hip/hip_bf16.h>
#include <math.h>

typedef __hip_bfloat16 bf16;
typedef __attribute__((ext_vector_type(8))) short short8;
typedef __attribute__((ext_vector_type(4))) float floatx4;

#define B_ 4
#define L_ 4096
#define D_ 512
#define M_ (B_*L_)   // 16384 rows

__device__ __forceinline__ float b2f(bf16 v){ return __bfloat162float(v); }
__device__ __forceinline__ bf16  f2b(float v){ return __float2bfloat16(v); }
__device__ __forceinline__ short f2bs(float v){ bf16 h = __float2bfloat16(v); short s; __builtin_memcpy(&s,&h,2); return s; }
__device__ __forceinline__ unsigned short f2bus(float v){ bf16 h = __float2bfloat16(v); unsigned short s; __builtin_memcpy(&s,&h,2); return s; }
__device__ __forceinline__ float bus2f(unsigned short u){ unsigned int x = ((unsigned int)u)<<16; float f; __builtin_memcpy(&f,&x,4); return f; }
__device__ __forceinline__ floatx4 fx4(float v){ floatx4 r; r.x=v; r.y=v; r.z=v; r.w=v; return r; }
__device__ __forceinline__ floatx4 us4f(ushort4 u){ floatx4 r; r.x=bus2f(u.x); r.y=bus2f(u.y); r.z=bus2f(u.z); r.w=bus2f(u.w); return r; }
__device__ __forceinline__ ushort4 f4us(floatx4 v){ ushort4 r; r.x=f2bus(v.x); r.y=f2bus(v.y); r.z=f2bus(v.z); r.w=f2bus(v.w); return r; }
__device__ __forceinline__ floatx4 exp4(floatx4 v){ floatx4 r; r.x=__expf(v.x); r.y=__expf(v.y); r.z=__expf(v.z); r.w=__expf(v.w); return r; }

#define GLD16(gp, lp) __builtin_amdgcn_global_load_lds( \
    (const __attribute__((address_space(1))) void*)(gp), \
    (__attribute__((address_space(3))) void*)(lp), 16, 0, 0)

// ---------------- weight transpose+downcast (K,N) f32 -> (N,K) bf16 ----------------
__global__ __launch_bounds__(1024) void k_transpose(const float* __restrict__ src,
                                                    bf16* __restrict__ dst, int K, int N){
    __shared__ float tile[32][33];
    int n0 = blockIdx.x*32, k0 = blockIdx.y*32;
    int tx = threadIdx.x, ty = threadIdx.y;
    tile[ty][tx] = src[(size_t)(k0+ty)*N + n0+tx];
    __syncthreads();
    ((short*)dst)[(size_t)(n0+ty)*K + k0+tx] = f2bs(tile[tx][ty]);
}

// ---------------- f32 -> bf16 bulk convert ----------------
__global__ __launch_bounds__(256) void k_cvt(const float* __restrict__ src,
                                             bf16* __restrict__ dst){
    size_t i = ((size_t)blockIdx.x*256 + threadIdx.x)*4;
    float4 v = *(const float4*)(src + i);
    short4 s; s.x=f2bs(v.x); s.y=f2bs(v.y); s.z=f2bs(v.z); s.w=f2bs(v.w);
    *(short4*)((short*)dst + i) = s;
}

// ---------------- 128-tile MFMA GEMM (m97 pattern), K=512, fused epilogues ----------------
// EPI 0: xproj  (bias; gc<512: xbarh bf16 ; gc>=512: silu->siluz)
// EPI 1: dt     (bias, softplus/clip, *A -> lah bf16)
// EPI 2: out    (bias -> f32 out)
// EPI 3: B/C proj, N=128 (cols 0-63 = B, 64-127 = C), fused rmsnorm(64) -> o1=Bm, o4=Cm
template<int EPI>
__global__ __launch_bounds__(256) void k_gemm(const bf16* __restrict__ Ap,
        const bf16* __restrict__ Wt, const float* __restrict__ bias,
        const float* __restrict__ aux,
        float* __restrict__ o1, bf16* __restrict__ o2, bf16* __restrict__ o3,
        float* __restrict__ o4){
    __shared__ short As[128*32];
    __shared__ short Bs[128*32];
    const int K = 512;
    int m0 = blockIdx.x*128, n0 = blockIdx.y*128;
    int tid=threadIdx.x, w=tid>>6, lane=tid&63;
    int wr=w>>1, wc=w&1, quad=lane>>4, r16=lane&15;
    floatx4 acc[4][4];
    #pragma unroll
    for (int i=0;i<4;i++)
        #pragma unroll
        for (int j=0;j<4;j++)
            #pragma unroll
            for (int e=0;e<4;e++) acc[i][j][e]=0.f;

    int c0 = tid, c1 = tid + 256;
    const short* Ab = (const short*)Ap + (size_t)m0*K;
    const short* Wb = (const short*)Wt + (size_t)n0*K;
    int r0 = c0>>2, g0 = (c0&3)*8;
    int r1 = c1>>2, g1 = (c1&3)*8;

    for (int k0=0;k0<K;k0+=32){
        GLD16(Ab + (size_t)r0*K + k0 + g0, &As[c0*8]);
        GLD16(Ab + (size_t)r1*K + k0 + g1, &As[c1*8]);
        GLD16(Wb + (size_t)r0*K + k0 + g0, &Bs[c0*8]);
        GLD16(Wb + (size_t)r1*K + k0 + g1, &Bs[c1*8]);
        __syncthreads();
        short8 af[4], bv[4];
        #pragma unroll
        for (int i=0;i<4;i++) af[i] = *(short8*)&As[(wr*64+i*16+r16)*32 + quad*8];
        #pragma unroll
        for (int j=0;j<4;j++) bv[j] = *(short8*)&Bs[(wc*64+j*16+r16)*32 + quad*8];
        #pragma unroll
        for (int i=0;i<4;i++)
            #pragma unroll
            for (int j=0;j<4;j++)
                acc[i][j] = __builtin_amdgcn_mfma_f32_16x16x32_bf16(af[i], bv[j], acc[i][j], 0,0,0);
        __syncthreads();
    }
    if (EPI==3){
        #pragma unroll
        for (int i=0;i<4;i++)
        #pragma unroll
        for (int reg=0;reg<4;reg++){
            float ss=0.f;
            #pragma unroll
            for (int j=0;j<4;j++){ float t=acc[i][j][reg]; ss+=t*t; }
            #pragma unroll
            for (int m=1;m<16;m<<=1) ss += __shfl_xor(ss, m, 64);
            float rq = rsqrtf(ss*(1.f/64.f)+1e-6f);
            int gr = m0 + wr*64 + i*16 + quad*4 + reg;
            #pragma unroll
            for (int j=0;j<4;j++){
                int gc = wc*64 + j*16 + r16;
                float gval = (gc<64) ? bias[gc] : aux[gc-64];
                float v = acc[i][j][reg]*rq*gval;
                if (gc<64) o1[(size_t)gr*64 + gc] = v;
                else       o4[(size_t)gr*64 + (gc-64)] = v;
            }
        }
        return;
    }
    #pragma unroll
    for (int i=0;i<4;i++)
    #pragma unroll
    for (int j=0;j<4;j++)
    #pragma unroll
    for (int reg=0;reg<4;reg++){
        int gr = m0 + wr*64 + i*16 + quad*4 + reg;
        int gc = n0 + wc*64 + j*16 + r16;
        float v = acc[i][j][reg] + bias[gc];
        if (EPI==0){
            if (gc < 512){
                o2[(size_t)gr*512 + gc] = f2b(v);
            } else {
                o3[(size_t)gr*512 + (gc-512)] = f2b(v / (1.f + __expf(-v)));
            }
        } else if (EPI==1){
            float sp = (v > 15.f) ? v : log1pf(__expf(v));
            float dt = fminf(fmaxf(sp, 1e-4f), 5.f);
            float Ad = -__expf(fminf(fmaxf(aux[gc], -20.f), 2.f));
            o2[(size_t)gr*512 + gc] = f2b(fminf(fmaxf(dt*Ad, -18.420680743952367f), 0.f));
        } else {
            o1[(size_t)gr*512 + gc] = v;
        }
    }
}

// ---------------- pass1: chunk-local final state (n-split, R=4 d/thread) ----------------
// grid (64 chunks, 4 batch, 2 n-halves), 128 thr; thread t -> d = 4t..4t+3.
__global__ __launch_bounds__(128) void k_pass1(const unsigned short* __restrict__ lah,
        const unsigned short* __restrict__ xh, const float* __restrict__ Bm,
        unsigned short* __restrict__ localh, float* __restrict__ atot){
    __shared__ float Bs[64*32];
    int c=blockIdx.x, b=blockIdx.y, nh=blockIdx.z;
    int d = threadIdx.x*4;
    size_t rowbase=(size_t)b*L_+(size_t)c*64;
    size_t cb=(size_t)c*4+b;
    #pragma unroll
    for (int it=0;it<4;it++){
        int idx=it*128+threadIdx.x;        // 512 float4s
        int row=idx>>3, grp=idx&7;
        *(float4*)&Bs[row*32+grp*4] = *(const float4*)(Bm + (rowbase+row)*64 + nh*32 + grp*4);
    }
    __syncthreads();
    floatx4 st[32];
    #pragma unroll
    for (int n=0;n<32;n++) st[n]=fx4(0.f);
    floatx4 cs=fx4(0.f);
    size_t off0=rowbase*512+d;
    #pragma unroll 1
    for (int i=0;i<64;i++){
        floatx4 lai = us4f(*(const ushort4*)(lah+off0+(size_t)i*512));
        floatx4 xi  = us4f(*(const ushort4*)(xh +off0+(size_t)i*512));
        floatx4 ai = exp4(lai);
        cs = cs + lai;
        const float* Br=Bs+i*32;
        #pragma unroll
        for (int k=0;k<8;k++){
            float4 bv=*(const float4*)(Br+k*4);
            st[k*4+0]=ai*st[k*4+0]+fx4(bv.x)*xi;
            st[k*4+1]=ai*st[k*4+1]+fx4(bv.y)*xi;
            st[k*4+2]=ai*st[k*4+2]+fx4(bv.z)*xi;
            st[k*4+3]=ai*st[k*4+3]+fx4(bv.w)*xi;
        }
    }
    #pragma unroll
    for (int n=0;n<32;n++)
        *(ushort4*)(localh + (cb*64 + nh*32 + n)*512 + d) = f4us(st[n]);
    if (nh==0){
        floatx4 at = exp4(cs);
        *(floatx4*)(atot + cb*512 + d) = at;
    }
}

// ---------------- sequential inter-chunk scan (in place, bf16 pairs) ----------------
__global__ __launch_bounds__(256) void k_scan(unsigned short* __restrict__ localh,
        const float* __restrict__ atot){
    int idx = blockIdx.x*256 + threadIdx.x;      // over b*n*(d/2) = 65536
    int d = (idx & 255)*2, n = (idx >> 8) & 63, b = idx >> 14;
    float sx=0.f, sy=0.f;
    for (int c=0;c<64;c++){
        size_t cb = (size_t)c*4 + b;
        size_t off = (cb*64 + n)*512 + d;
        ushort2 v = *(ushort2*)(localh+off);
        float vx=bus2f(v.x), vy=bus2f(v.y);
        ushort2 wp; wp.x=f2bus(sx); wp.y=f2bus(sy);
        *(ushort2*)(localh+off) = wp;             // state entering chunk c
        float2 at = *(const float2*)(atot + cb*512 + d);
        sx = sx*at.x + vx; sy = sy*at.y + vy;
        if (!isfinite(sx)) sx = 0.f;
        if (!isfinite(sy)) sy = 0.f;
    }
}

// ---------------- pass2: recurrence seeded by Sprev -> partial y bf16 (n-split, R=4) ----
__global__ __launch_bounds__(128) void k_pass2(const unsigned short* __restrict__ lah,
        const unsigned short* __restrict__ xh, const float* __restrict__ Bm,
        const float* __restrict__ Cm, const unsigned short* __restrict__ Sprevh,
        unsigned short* __restrict__ ybuf){
    __shared__ float Bs[64*32];
    __shared__ float Cs[64*32];
    int c=blockIdx.x, b=blockIdx.y, nh=blockIdx.z;
    int d = threadIdx.x*4;
    size_t rowbase=(size_t)b*L_+(size_t)c*64;
    size_t cb=(size_t)c*4+b;
    #pragma unroll
    for (int it=0;it<4;it++){
        int idx=it*128+threadIdx.x;
        int row=idx>>3, grp=idx&7;
        *(float4*)&Bs[row*32+grp*4] = *(const float4*)(Bm + (rowbase+row)*64 + nh*32 + grp*4);
        *(float4*)&Cs[row*32+grp*4] = *(const float4*)(Cm + (rowbase+row)*64 + nh*32 + grp*4);
    }
    floatx4 st[32];
    #pragma unroll
    for (int n=0;n<32;n++)
        st[n] = us4f(*(const ushort4*)(Sprevh + (cb*64 + nh*32 + n)*512 + d));
    __syncthreads();
    size_t off0=rowbase*512+d;
    unsigned short* yout = ybuf + (size_t)nh*M_*512;
    #pragma unroll 1
    for (int i=0;i<64;i++){
        floatx4 lai = us4f(*(const ushort4*)(lah+off0+(size_t)i*512));
        floatx4 xi  = us4f(*(const ushort4*)(xh +off0+(size_t)i*512));
        floatx4 ai = exp4(lai);
        const float* Br=Bs+i*32;
        const float* Cr=Cs+i*32;
        floatx4 yv=fx4(0.f);
        #pragma unroll
        for (int k=0;k<8;k++){
            float4 bv=*(const float4*)(Br+k*4);
            float4 cv=*(const float4*)(Cr+k*4);
            floatx4 s;
            s=ai*st[k*4+0]+fx4(bv.x)*xi; st[k*4+0]=s; yv=yv+fx4(cv.x)*s;
            s=ai*st[k*4+1]+fx4(bv.y)*xi; st[k*4+1]=s; yv=yv+fx4(cv.y)*s;
            s=ai*st[k*4+2]+fx4(bv.z)*xi; st[k*4+2]=s; yv=yv+fx4(cv.z)*s;
            s=ai*st[k*4+3]+fx4(bv.w)*xi; st[k*4+3]=s; yv=yv+fx4(cv.w)*s;
        }
        *(ushort4*)(yout + off0 + (size_t)i*512) = f4us(yv);
    }
}

// ---------------- +D_skip*xbar, rmsnorm(d=512), *silu(z) -> u (bf16) ----------------
__global__ __launch_bounds__(256) void k_outnorm(const unsigned short* __restrict__ yA,
        const unsigned short* __restrict__ yB,
        const bf16* __restrict__ xbarh, const float* __restrict__ Dskip,
        const float* __restrict__ g, const bf16* __restrict__ siluz,
        bf16* __restrict__ u){
    int wave = threadIdx.x >> 6, lane = threadIdx.x & 63;
    size_t row = (size_t)blockIdx.x*4 + wave;
    float v[8]; float ss = 0.f;
    #pragma unroll
    for (int j=0;j<8;j++){
        int d = j*64 + lane;
        float yv = bus2f(yA[row*512 + d]) + bus2f(yB[row*512 + d]);
        if (!isfinite(yv)) yv = 0.f;
        float t = yv + Dskip[d] * b2f(xbarh[row*512 + d]);
        v[j] = t; ss += t*t;
    }
    #pragma unroll
    for (int m=1;m<64;m<<=1) ss += __shfl_xor(ss, m, 64);
    float r = rsqrtf(ss*(1.f/512.f) + 1e-6f);
    #pragma unroll
    for (int j=0;j<8;j++){
        int d = j*64 + lane;
        u[row*512 + d] = f2b(v[j] * r * g[d] * b2f(siluz[row*512 + d]));
    }
}

extern "C" void kernel_launch(void* const* d_in, const int* in_sizes, int n_in,
                              void* d_out, int out_size, void* d_ws, size_t ws_size,
                              hipStream_t stream){
    const float* x       = (const float*)d_in[0];
    const float* A_log   = (const float*)d_in[1];
    const float* dt_bias = (const float*)d_in[2];
    const float* D_skip  = (const float*)d_in[3];
    const float* W_xproj = (const float*)d_in[4];
    const float* b_xproj = (const float*)d_in[5];
    const float* W_B     = (const float*)d_in[6];
    const float* W_C     = (const float*)d_in[7];
    const float* W_dt    = (const float*)d_in[8];
    const float* g_B     = (const float*)d_in[9];
    const float* g_C     = (const float*)d_in[10];
    const float* g_out   = (const float*)d_in[11];
    const float* W_out   = (const float*)d_in[12];
    const float* b_out   = (const float*)d_in[13];
    float* out = (float*)d_out;

    char* wp = (char*)d_ws;
    auto alloc = [&](size_t bytes)->char*{ char* p = wp; wp += (bytes + 255) & ~(size_t)255; return p; };
    bf16*  xh    = (bf16*) alloc((size_t)M_*512*2);
    bf16*  xbarh = (bf16*) alloc((size_t)M_*512*2);
    bf16*  siluz = (bf16*) alloc((size_t)M_*512*2);
    bf16*  lah   = (bf16*) alloc((size_t)M_*512*2);
    float* Bm    = (float*)alloc((size_t)M_*64*4);
    float* Cm    = (float*)alloc((size_t)M_*64*4);
    unsigned short* localh = (unsigned short*)alloc((size_t)256*64*512*2);  // bf16 states
    float* atot  = (float*)alloc((size_t)256*512*4);
    unsigned short* ybuf = (unsigned short*)alloc((size_t)2*M_*512*2);      // bf16 partials
    bf16*  u     = (bf16*) alloc((size_t)M_*512*2);
    bf16*  WtX   = (bf16*) alloc((size_t)1024*512*2);
    bf16*  WtD   = (bf16*) alloc((size_t)512*512*2);
    bf16*  WtO   = (bf16*) alloc((size_t)512*512*2);
    bf16*  WtBC  = (bf16*) alloc((size_t)128*512*2);

    dim3 tb(32,32);
    k_transpose<<<dim3(32,16), tb, 0, stream>>>(W_xproj, WtX, 512, 1024);
    k_transpose<<<dim3(16,16), tb, 0, stream>>>(W_dt,   WtD, 512, 512);
    k_transpose<<<dim3(16,16), tb, 0, stream>>>(W_out,  WtO, 512, 512);
    k_transpose<<<dim3(2,16),  tb, 0, stream>>>(W_B,    WtBC,          512, 64);
    k_transpose<<<dim3(2,16),  tb, 0, stream>>>(W_C,    WtBC+64*512,   512, 64);
    k_cvt      <<<M_*512/1024, 256, 0, stream>>>(x, xh);

    k_gemm<0> <<<dim3(128, 8), 256, 0, stream>>>(xh,    WtX,  b_xproj, nullptr, nullptr, xbarh, siluz, nullptr);
    k_gemm<3> <<<dim3(128, 1), 256, 0, stream>>>(xbarh, WtBC, g_B, g_C, Bm, nullptr, nullptr, Cm);
    k_gemm<1> <<<dim3(128, 4), 256, 0, stream>>>(xbarh, WtD,  dt_bias, A_log, nullptr, lah, nullptr, nullptr);
    k_pass1   <<<dim3(64,4,2), 128, 0, stream>>>((const unsigned short*)lah, (const unsigned short*)xbarh, Bm, localh, atot);
    k_scan    <<<256,          256, 0, stream>>>(localh, atot);
    k_pass2   <<<dim3(64,4,2), 128, 0, stream>>>((const unsigned short*)lah, (const unsigned short*)xbarh, Bm, Cm, localh, ybuf);
    k_outnorm <<<M_/4,         256, 0, stream>>>(ybuf, ybuf+(size_t)M_*512, xbarh, D_skip, g_out, siluz, u);
    k_gemm<2> <<<dim3(128, 4), 256, 0, stream>>>(u,     WtO,  b_out, nullptr, out, nullptr, nullptr, nullptr);
}

// Round 8
// 353.422 us; speedup vs baseline: 1.0811x; 1.0811x over previous
//
#include <hip/hip_runtime.h>
#include <hip/hip_bf16.h>
#include <math.h>

typedef __hip_bfloat16 bf16;
typedef __attribute__((ext_vector_type(8))) short short8;
typedef __attribute__((ext_vector_type(4))) float floatx4;

#define B_ 4
#define L_ 4096
#define D_ 512
#define M_ (B_*L_)   // 16384 rows

__device__ __forceinline__ float b2f(bf16 v){ return __bfloat162float(v); }
__device__ __forceinline__ bf16  f2b(float v){ return __float2bfloat16(v); }
__device__ __forceinline__ short f2bs(float v){ bf16 h = __float2bfloat16(v); short s; __builtin_memcpy(&s,&h,2); return s; }
__device__ __forceinline__ unsigned short f2bus(float v){ bf16 h = __float2bfloat16(v); unsigned short s; __builtin_memcpy(&s,&h,2); return s; }
__device__ __forceinline__ float bus2f(unsigned short u){ unsigned int x = ((unsigned int)u)<<16; float f; __builtin_memcpy(&f,&x,4); return f; }
__device__ __forceinline__ floatx4 fx4(float v){ floatx4 r; r.x=v; r.y=v; r.z=v; r.w=v; return r; }
__device__ __forceinline__ floatx4 us4f(ushort4 u){ floatx4 r; r.x=bus2f(u.x); r.y=bus2f(u.y); r.z=bus2f(u.z); r.w=bus2f(u.w); return r; }
__device__ __forceinline__ ushort4 f4us(floatx4 v){ ushort4 r; r.x=f2bus(v.x); r.y=f2bus(v.y); r.z=f2bus(v.z); r.w=f2bus(v.w); return r; }
__device__ __forceinline__ floatx4 exp4(floatx4 v){ floatx4 r; r.x=__expf(v.x); r.y=__expf(v.y); r.z=__expf(v.z); r.w=__expf(v.w); return r; }

#define GLD16(gp, lp) __builtin_amdgcn_global_load_lds( \
    (const __attribute__((address_space(1))) void*)(gp), \
    (__attribute__((address_space(3))) void*)(lp), 16, 0, 0)

// ---------------- k_prep: all weight transposes + x convert, one launch ----------------
// blocks 0..1087: 32x32 transpose tiles; 1088..3135: x f32->bf16 (4096 elems/block)
__global__ __launch_bounds__(1024) void k_prep(const float* __restrict__ x, bf16* __restrict__ xh,
        const float* __restrict__ WX, const float* __restrict__ WD, const float* __restrict__ WO,
        const float* __restrict__ WB, const float* __restrict__ WC,
        bf16* __restrict__ WtX, bf16* __restrict__ WtD, bf16* __restrict__ WtO,
        bf16* __restrict__ WtBC){
    __shared__ float tile[32][33];
    int bx = blockIdx.x;
    if (bx < 1088){
        const float* src; bf16* dst; int N, t;
        if (bx < 512)      { src=WX; dst=WtX;  N=1024; t=bx; }
        else if (bx < 768) { src=WD; dst=WtD;  N=512;  t=bx-512; }
        else if (bx < 1024){ src=WO; dst=WtO;  N=512;  t=bx-768; }
        else if (bx < 1056){ src=WB; dst=WtBC; N=64;   t=bx-1024; }
        else               { src=WC; dst=WtBC+(size_t)64*512; N=64; t=bx-1056; }
        int ntiles = N >> 5;
        int n0 = (t & (ntiles-1))*32, k0 = (t/ntiles)*32;
        int tx = threadIdx.x & 31, ty = threadIdx.x >> 5;
        tile[ty][tx] = src[(size_t)(k0+ty)*N + n0+tx];
        __syncthreads();
        ((short*)dst)[(size_t)(n0+ty)*512 + k0+tx] = f2bs(tile[tx][ty]);
    } else {
        size_t i = ((size_t)(bx-1088)*1024 + threadIdx.x)*4;
        float4 v = *(const float4*)(x + i);
        short4 s; s.x=f2bs(v.x); s.y=f2bs(v.y); s.z=f2bs(v.z); s.w=f2bs(v.w);
        *(short4*)((short*)xh + i) = s;
    }
}

// ---------------- 128-tile MFMA GEMM (m97 pattern), K=512, fused epilogues ----------------
// EPI 0: xproj (bias; gc<512: xbarh bf16 ; gc>=512: silu->siluz)
// EPI 1: dt    (bias, softplus/clip, *A -> lah bf16)
// EPI 2: out   (bias -> f32 out)
// EPI 3: B/C proj, N=128 (cols 0-63 = B, 64-127 = C), fused rmsnorm(64) -> o1=Bm, o4=Cm
template<int EPI>
__global__ __launch_bounds__(256) void k_gemm(const bf16* __restrict__ Ap,
        const bf16* __restrict__ Wt, const float* __restrict__ bias,
        const float* __restrict__ aux,
        float* __restrict__ o1, bf16* __restrict__ o2, bf16* __restrict__ o3,
        float* __restrict__ o4){
    __shared__ short As[128*32];
    __shared__ short Bs[128*32];
    const int K = 512;
    int m0 = blockIdx.x*128, n0 = blockIdx.y*128;
    int tid=threadIdx.x, w=tid>>6, lane=tid&63;
    int wr=w>>1, wc=w&1, quad=lane>>4, r16=lane&15;
    floatx4 acc[4][4];
    #pragma unroll
    for (int i=0;i<4;i++)
        #pragma unroll
        for (int j=0;j<4;j++)
            #pragma unroll
            for (int e=0;e<4;e++) acc[i][j][e]=0.f;

    int c0 = tid, c1 = tid + 256;
    const short* Ab = (const short*)Ap + (size_t)m0*K;
    const short* Wb = (const short*)Wt + (size_t)n0*K;
    int r0 = c0>>2, g0 = (c0&3)*8;
    int r1 = c1>>2, g1 = (c1&3)*8;

    for (int k0=0;k0<K;k0+=32){
        GLD16(Ab + (size_t)r0*K + k0 + g0, &As[c0*8]);
        GLD16(Ab + (size_t)r1*K + k0 + g1, &As[c1*8]);
        GLD16(Wb + (size_t)r0*K + k0 + g0, &Bs[c0*8]);
        GLD16(Wb + (size_t)r1*K + k0 + g1, &Bs[c1*8]);
        __syncthreads();
        short8 af[4], bv[4];
        #pragma unroll
        for (int i=0;i<4;i++) af[i] = *(short8*)&As[(wr*64+i*16+r16)*32 + quad*8];
        #pragma unroll
        for (int j=0;j<4;j++) bv[j] = *(short8*)&Bs[(wc*64+j*16+r16)*32 + quad*8];
        #pragma unroll
        for (int i=0;i<4;i++)
            #pragma unroll
            for (int j=0;j<4;j++)
                acc[i][j] = __builtin_amdgcn_mfma_f32_16x16x32_bf16(af[i], bv[j], acc[i][j], 0,0,0);
        __syncthreads();
    }
    if (EPI==3){
        #pragma unroll
        for (int i=0;i<4;i++)
        #pragma unroll
        for (int reg=0;reg<4;reg++){
            float ss=0.f;
            #pragma unroll
            for (int j=0;j<4;j++){ float t=acc[i][j][reg]; ss+=t*t; }
            #pragma unroll
            for (int m=1;m<16;m<<=1) ss += __shfl_xor(ss, m, 64);
            float rq = rsqrtf(ss*(1.f/64.f)+1e-6f);
            int gr = m0 + wr*64 + i*16 + quad*4 + reg;
            #pragma unroll
            for (int j=0;j<4;j++){
                int gc = wc*64 + j*16 + r16;
                float gval = (gc<64) ? bias[gc] : aux[gc-64];
                float v = acc[i][j][reg]*rq*gval;
                if (gc<64) o1[(size_t)gr*64 + gc] = v;
                else       o4[(size_t)gr*64 + (gc-64)] = v;
            }
        }
        return;
    }
    #pragma unroll
    for (int i=0;i<4;i++)
    #pragma unroll
    for (int j=0;j<4;j++)
    #pragma unroll
    for (int reg=0;reg<4;reg++){
        int gr = m0 + wr*64 + i*16 + quad*4 + reg;
        int gc = n0 + wc*64 + j*16 + r16;
        float v = acc[i][j][reg] + bias[gc];
        if (EPI==0){
            if (gc < 512){
                o2[(size_t)gr*512 + gc] = f2b(v);
            } else {
                o3[(size_t)gr*512 + (gc-512)] = f2b(v / (1.f + __expf(-v)));
            }
        } else if (EPI==1){
            float sp = (v > 15.f) ? v : log1pf(__expf(v));
            float dt = fminf(fmaxf(sp, 1e-4f), 5.f);
            float Ad = -__expf(fminf(fmaxf(aux[gc], -20.f), 2.f));
            o2[(size_t)gr*512 + gc] = f2b(fminf(fmaxf(dt*Ad, -18.420680743952367f), 0.f));
        } else {
            o1[(size_t)gr*512 + gc] = v;
        }
    }
}

// one recurrence row: st = ai*st + b*xi  (and y += c*st if YACC)
template<bool YACC>
__device__ __forceinline__ void row_step(floatx4* st, const float4* Bb, const float4* Cb,
        floatx4 ai, floatx4 xi, floatx4& yv){
    #pragma unroll
    for (int k=0;k<8;k++){
        float4 bv=Bb[k];
        floatx4 s;
        s=ai*st[k*4+0]+fx4(bv.x)*xi; st[k*4+0]=s; if (YACC) yv=yv+fx4(Cb[k].x)*s;
        s=ai*st[k*4+1]+fx4(bv.y)*xi; st[k*4+1]=s; if (YACC) yv=yv+fx4(Cb[k].y)*s;
        s=ai*st[k*4+2]+fx4(bv.z)*xi; st[k*4+2]=s; if (YACC) yv=yv+fx4(Cb[k].z)*s;
        s=ai*st[k*4+3]+fx4(bv.w)*xi; st[k*4+3]=s; if (YACC) yv=yv+fx4(Cb[k].w)*s;
    }
}

// ---------------- pass1: chunk-local final state (n-split, R=4, sw-pipelined) ----------
// grid (64,4,2), 128 thr; thread t -> d = 4t..4t+3.
__global__ __launch_bounds__(128) void k_pass1(const unsigned short* __restrict__ lah,
        const unsigned short* __restrict__ xh, const float* __restrict__ Bm,
        unsigned short* __restrict__ localh, float* __restrict__ atot){
    __shared__ float Bsh[64*32];
    int c=blockIdx.x, b=blockIdx.y, nh=blockIdx.z;
    int d = threadIdx.x*4;
    size_t rowbase=(size_t)b*L_+(size_t)c*64;
    size_t cb=(size_t)c*4+b;
    #pragma unroll
    for (int it=0;it<4;it++){
        int idx=it*128+threadIdx.x;
        int row=idx>>3, grp=idx&7;
        *(float4*)&Bsh[row*32+grp*4] = *(const float4*)(Bm + (rowbase+row)*64 + nh*32 + grp*4);
    }
    __syncthreads();
    floatx4 st[32];
    #pragma unroll
    for (int n=0;n<32;n++) st[n]=fx4(0.f);
    floatx4 cs=fx4(0.f);
    size_t off0=rowbase*512+d;
    ushort4 laA=*(const ushort4*)(lah+off0),     xA=*(const ushort4*)(xh+off0);
    ushort4 laB=*(const ushort4*)(lah+off0+512), xB=*(const ushort4*)(xh+off0+512);
    float4 Ab[8], Bb[8];
    #pragma unroll
    for (int k=0;k<8;k++) Ab[k]=*(const float4*)&Bsh[k*4];
    floatx4 dummy;
    for (int i=0;i<64;i+=2){
        int r2 = (i+2<64)? i+2 : 63;
        int r3 = (i+3<64)? i+3 : 63;
        floatx4 la1=us4f(laA), x1=us4f(xA);
        laA=*(const ushort4*)(lah+off0+(size_t)r2*512); xA=*(const ushort4*)(xh+off0+(size_t)r2*512);
        #pragma unroll
        for (int k=0;k<8;k++) Bb[k]=*(const float4*)&Bsh[(i+1)*32+k*4];
        cs = cs + la1;
        row_step<false>(st, Ab, nullptr, exp4(la1), x1, dummy);

        floatx4 la2=us4f(laB), x2=us4f(xB);
        laB=*(const ushort4*)(lah+off0+(size_t)r3*512); xB=*(const ushort4*)(xh+off0+(size_t)r3*512);
        #pragma unroll
        for (int k=0;k<8;k++) Ab[k]=*(const float4*)&Bsh[r2*32+k*4];
        cs = cs + la2;
        row_step<false>(st, Bb, nullptr, exp4(la2), x2, dummy);
    }
    #pragma unroll
    for (int n=0;n<32;n++)
        *(ushort4*)(localh + (cb*64 + nh*32 + n)*512 + d) = f4us(st[n]);
    if (nh==0)
        *(floatx4*)(atot + cb*512 + d) = exp4(cs);
}

// ---------------- sequential inter-chunk scan (in place, bf16 pairs) ----------------
__global__ __launch_bounds__(256) void k_scan(unsigned short* __restrict__ localh,
        const float* __restrict__ atot){
    int idx = blockIdx.x*256 + threadIdx.x;      // over b*n*(d/2) = 65536
    int d = (idx & 255)*2, n = (idx >> 8) & 63, b = idx >> 14;
    float sx=0.f, sy=0.f;
    for (int c=0;c<64;c++){
        size_t cb = (size_t)c*4 + b;
        size_t off = (cb*64 + n)*512 + d;
        ushort2 v = *(ushort2*)(localh+off);
        float vx=bus2f(v.x), vy=bus2f(v.y);
        ushort2 wp; wp.x=f2bus(sx); wp.y=f2bus(sy);
        *(ushort2*)(localh+off) = wp;             // state entering chunk c
        float2 at = *(const float2*)(atot + cb*512 + d);
        sx = sx*at.x + vx; sy = sy*at.y + vy;
        if (!isfinite(sx)) sx = 0.f;
        if (!isfinite(sy)) sy = 0.f;
    }
}

// ---------------- pass2: recurrence seeded by Sprev -> partial y bf16 (sw-pipelined) ----
__global__ __launch_bounds__(128) void k_pass2(const unsigned short* __restrict__ lah,
        const unsigned short* __restrict__ xh, const float* __restrict__ Bm,
        const float* __restrict__ Cm, const unsigned short* __restrict__ Sprevh,
        unsigned short* __restrict__ ybuf){
    __shared__ float Bsh[64*32];
    __shared__ float Csh[64*32];
    int c=blockIdx.x, b=blockIdx.y, nh=blockIdx.z;
    int d = threadIdx.x*4;
    size_t rowbase=(size_t)b*L_+(size_t)c*64;
    size_t cb=(size_t)c*4+b;
    #pragma unroll
    for (int it=0;it<4;it++){
        int idx=it*128+threadIdx.x;
        int row=idx>>3, grp=idx&7;
        *(float4*)&Bsh[row*32+grp*4] = *(const float4*)(Bm + (rowbase+row)*64 + nh*32 + grp*4);
        *(float4*)&Csh[row*32+grp*4] = *(const float4*)(Cm + (rowbase+row)*64 + nh*32 + grp*4);
    }
    floatx4 st[32];
    #pragma unroll
    for (int n=0;n<32;n++)
        st[n] = us4f(*(const ushort4*)(Sprevh + (cb*64 + nh*32 + n)*512 + d));
    __syncthreads();
    size_t off0=rowbase*512+d;
    unsigned short* yout = ybuf + (size_t)nh*M_*512;
    ushort4 laA=*(const ushort4*)(lah+off0),     xA=*(const ushort4*)(xh+off0);
    ushort4 laB=*(const ushort4*)(lah+off0+512), xB=*(const ushort4*)(xh+off0+512);
    float4 Ab[8], Ac[8], Bb[8], Bc[8];
    #pragma unroll
    for (int k=0;k<8;k++){ Ab[k]=*(const float4*)&Bsh[k*4]; Ac[k]=*(const float4*)&Csh[k*4]; }
    for (int i=0;i<64;i+=2){
        int r2 = (i+2<64)? i+2 : 63;
        int r3 = (i+3<64)? i+3 : 63;
        floatx4 la1=us4f(laA), x1=us4f(xA);
        laA=*(const ushort4*)(lah+off0+(size_t)r2*512); xA=*(const ushort4*)(xh+off0+(size_t)r2*512);
        #pragma unroll
        for (int k=0;k<8;k++){ Bb[k]=*(const float4*)&Bsh[(i+1)*32+k*4]; Bc[k]=*(const float4*)&Csh[(i+1)*32+k*4]; }
        floatx4 yv=fx4(0.f);
        row_step<true>(st, Ab, Ac, exp4(la1), x1, yv);
        *(ushort4*)(yout+off0+(size_t)i*512)=f4us(yv);

        floatx4 la2=us4f(laB), x2=us4f(xB);
        laB=*(const ushort4*)(lah+off0+(size_t)r3*512); xB=*(const ushort4*)(xh+off0+(size_t)r3*512);
        #pragma unroll
        for (int k=0;k<8;k++){ Ab[k]=*(const float4*)&Bsh[r2*32+k*4]; Ac[k]=*(const float4*)&Csh[r2*32+k*4]; }
        floatx4 yv2=fx4(0.f);
        row_step<true>(st, Bb, Bc, exp4(la2), x2, yv2);
        *(ushort4*)(yout+off0+(size_t)(i+1)*512)=f4us(yv2);
    }
}

// ---------------- +D_skip*xbar, rmsnorm(d=512), *silu(z) -> u (bf16) ----------------
__global__ __launch_bounds__(256) void k_outnorm(const unsigned short* __restrict__ yA,
        const unsigned short* __restrict__ yB,
        const bf16* __restrict__ xbarh, const float* __restrict__ Dskip,
        const float* __restrict__ g, const bf16* __restrict__ siluz,
        bf16* __restrict__ u){
    int wave = threadIdx.x >> 6, lane = threadIdx.x & 63;
    size_t row = (size_t)blockIdx.x*4 + wave;
    float v[8]; float ss = 0.f;
    #pragma unroll
    for (int j=0;j<8;j++){
        int d = j*64 + lane;
        float yv = bus2f(yA[row*512 + d]) + bus2f(yB[row*512 + d]);
        if (!isfinite(yv)) yv = 0.f;
        float t = yv + Dskip[d] * b2f(xbarh[row*512 + d]);
        v[j] = t; ss += t*t;
    }
    #pragma unroll
    for (int m=1;m<64;m<<=1) ss += __shfl_xor(ss, m, 64);
    float r = rsqrtf(ss*(1.f/512.f) + 1e-6f);
    #pragma unroll
    for (int j=0;j<8;j++){
        int d = j*64 + lane;
        u[row*512 + d] = f2b(v[j] * r * g[d] * b2f(siluz[row*512 + d]));
    }
}

extern "C" void kernel_launch(void* const* d_in, const int* in_sizes, int n_in,
                              void* d_out, int out_size, void* d_ws, size_t ws_size,
                              hipStream_t stream){
    const float* x       = (const float*)d_in[0];
    const float* A_log   = (const float*)d_in[1];
    const float* dt_bias = (const float*)d_in[2];
    const float* D_skip  = (const float*)d_in[3];
    const float* W_xproj = (const float*)d_in[4];
    const float* b_xproj = (const float*)d_in[5];
    const float* W_B     = (const float*)d_in[6];
    const float* W_C     = (const float*)d_in[7];
    const float* W_dt    = (const float*)d_in[8];
    const float* g_B     = (const float*)d_in[9];
    const float* g_C     = (const float*)d_in[10];
    const float* g_out   = (const float*)d_in[11];
    const float* W_out   = (const float*)d_in[12];
    const float* b_out   = (const float*)d_in[13];
    float* out = (float*)d_out;

    char* wp = (char*)d_ws;
    auto alloc = [&](size_t bytes)->char*{ char* p = wp; wp += (bytes + 255) & ~(size_t)255; return p; };
    bf16*  xh    = (bf16*) alloc((size_t)M_*512*2);
    bf16*  xbarh = (bf16*) alloc((size_t)M_*512*2);
    bf16*  siluz = (bf16*) alloc((size_t)M_*512*2);
    bf16*  lah   = (bf16*) alloc((size_t)M_*512*2);
    float* Bm    = (float*)alloc((size_t)M_*64*4);
    float* Cm    = (float*)alloc((size_t)M_*64*4);
    unsigned short* localh = (unsigned short*)alloc((size_t)256*64*512*2);  // bf16 states
    float* atot  = (float*)alloc((size_t)256*512*4);
    unsigned short* ybuf = (unsigned short*)alloc((size_t)2*M_*512*2);      // bf16 partials
    bf16*  u     = (bf16*) alloc((size_t)M_*512*2);
    bf16*  WtX   = (bf16*) alloc((size_t)1024*512*2);
    bf16*  WtD   = (bf16*) alloc((size_t)512*512*2);
    bf16*  WtO   = (bf16*) alloc((size_t)512*512*2);
    bf16*  WtBC  = (bf16*) alloc((size_t)128*512*2);

    k_prep    <<<3136, 1024, 0, stream>>>(x, xh, W_xproj, W_dt, W_out, W_B, W_C,
                                          WtX, WtD, WtO, WtBC);
    k_gemm<0> <<<dim3(128, 8), 256, 0, stream>>>(xh,    WtX,  b_xproj, nullptr, nullptr, xbarh, siluz, nullptr);
    k_gemm<3> <<<dim3(128, 1), 256, 0, stream>>>(xbarh, WtBC, g_B, g_C, Bm, nullptr, nullptr, Cm);
    k_gemm<1> <<<dim3(128, 4), 256, 0, stream>>>(xbarh, WtD,  dt_bias, A_log, nullptr, lah, nullptr, nullptr);
    k_pass1   <<<dim3(64,4,2), 128, 0, stream>>>((const unsigned short*)lah, (const unsigned short*)xbarh, Bm, localh, atot);
    k_scan    <<<256,          256, 0, stream>>>(localh, atot);
    k_pass2   <<<dim3(64,4,2), 128, 0, stream>>>((const unsigned short*)lah, (const unsigned short*)xbarh, Bm, Cm, localh, ybuf);
    k_outnorm <<<M_/4,         256, 0, stream>>>(ybuf, ybuf+(size_t)M_*512, xbarh, D_skip, g_out, siluz, u);
    k_gemm<2> <<<dim3(128, 4), 256, 0, stream>>>(u,     WtO,  b_out, nullptr, out, nullptr, nullptr, nullptr);
}